// Round 5
// baseline (3672.611 us; speedup 1.0000x reference)
//
#include <hip/hip_runtime.h>

typedef unsigned short u16;
typedef __attribute__((ext_vector_type(4))) float f32x4;
typedef __attribute__((ext_vector_type(8))) __bf16 bf16x8;
typedef __attribute__((ext_vector_type(8))) unsigned short u16x8;
typedef __attribute__((ext_vector_type(4))) unsigned short u16x4;

#define DI static __device__ __forceinline__

DI float bfu2f(u16 u){ unsigned int x = ((unsigned int)u)<<16; float f; __builtin_memcpy(&f,&x,4); return f; }
DI u16 f2bfu(float f){ __bf16 h = (__bf16)f; u16 u; __builtin_memcpy(&u,&h,2); return u; }
DI float sigm(float x){ return 1.f/(1.f+expf(-x)); }

DI void gload_lds16(const void* g, void* l) {
  __builtin_amdgcn_global_load_lds(
      (const __attribute__((address_space(1))) unsigned int*)g,
      (__attribute__((address_space(3))) unsigned int*)l, 16, 0, 0);
}

// ================= big GEMM: 128x128 tile, global_load_lds staging =================
// C[M,N] = A[M,K](bf16) @ Bt[N,K](bf16)^T.  Requires M%128==0, N%128==0, K%64==0.
template<bool OBF16>
__global__ __launch_bounds__(256) void gemm128_k(
    const u16* __restrict__ A, const u16* __restrict__ Bt,
    void* __restrict__ Cp, int M, int N, int K)
{
  __shared__ alignas(16) u16 As[128*64];
  __shared__ alignas(16) u16 Bs[128*64];
  const int tid = threadIdx.x;
  const int wid = tid >> 6, lane = tid & 63;
  const int wm = wid >> 1, wn = wid & 1;
  const int l15 = lane & 15, q = lane >> 4;
  const int m0 = blockIdx.x * 128, n0 = blockIdx.y * 128;
  const int sr = (wid << 3) + (lane >> 3);   // staging row within 32-row round
  const int sc = (lane & 7) << 3;            // staging col (bf16 elems)
  f32x4 acc[4][4];
  #pragma unroll
  for (int i=0;i<4;i++)
    #pragma unroll
    for (int j=0;j<4;j++) acc[i][j] = f32x4{0.f,0.f,0.f,0.f};

  char* la = (char*)As + (size_t)wid*1024;
  char* lb = (char*)Bs + (size_t)wid*1024;
  for (int k0 = 0; k0 < K; k0 += 64) {
    const u16* ga = A  + (size_t)(m0 + sr)*K + k0 + sc;
    const u16* gb = Bt + (size_t)(n0 + sr)*K + k0 + sc;
    #pragma unroll
    for (int it = 0; it < 4; ++it) {
      gload_lds16(ga + (size_t)(32*it)*K, la + it*4096);
      gload_lds16(gb + (size_t)(32*it)*K, lb + it*4096);
    }
    __syncthreads();
    #pragma unroll
    for (int ks = 0; ks < 64; ks += 32) {
      bf16x8 af[4], bfv[4];
      #pragma unroll
      for (int i=0;i<4;i++) af[i]  = *(const bf16x8*)&As[(wm*64 + i*16 + l15)*64 + ks + q*8];
      #pragma unroll
      for (int j=0;j<4;j++) bfv[j] = *(const bf16x8*)&Bs[(wn*64 + j*16 + l15)*64 + ks + q*8];
      #pragma unroll
      for (int i=0;i<4;i++)
        #pragma unroll
        for (int j=0;j<4;j++)
          acc[i][j] = __builtin_amdgcn_mfma_f32_16x16x32_bf16(af[i], bfv[j], acc[i][j], 0, 0, 0);
    }
    __syncthreads();
  }
  // C/D map: row=(lane>>4)*4+reg, col=lane&15  [m89-verified]
  #pragma unroll
  for (int i=0;i<4;i++)
    #pragma unroll
    for (int j=0;j<4;j++)
      #pragma unroll
      for (int rr=0;rr<4;rr++) {
        const int gm = m0 + wm*64 + i*16 + q*4 + rr;
        const int gn = n0 + wn*64 + j*16 + l15;
        const size_t o = (size_t)gm * (size_t)N + gn;
        if constexpr (OBF16) ((u16*)Cp)[o] = f2bfu(acc[i][j][rr]);
        else                 ((float*)Cp)[o] = acc[i][j][rr];
      }
}

// ================= small GEMM (64x64 tile) =================
// EPI: 0 none; 1 v-blend (dxp=vfirst, mixp=v0, Cp f32 RMW);
//      2 w-transform (mixp=w0, f32 out); 3 a-sigmoid (mixp=a0, bf16 out);
//      4 tanh (bf16 out); 5 sigmoid (bf16 out)
constexpr int LDW = 72;

template<bool MIX, bool WNK, bool ABF16, bool OBF16, int EPI=0>
__global__ __launch_bounds__(256) void gemm_k(
    const void* __restrict__ Ap, const float* __restrict__ dxp, const float* __restrict__ mixp,
    const float* __restrict__ Wp, void* __restrict__ Cp, int M, int N, int K)
{
  __shared__ alignas(16) __bf16 As[64*LDW];
  __shared__ alignas(16) __bf16 Bs[64*LDW];
  const int tid = threadIdx.x;
  const int m0 = blockIdx.x * 64;
  const int n0 = blockIdx.y * 64;
  const int lane = tid & 63, wid = tid >> 6;
  const int wm = wid >> 1, wn = wid & 1;
  const int l15 = lane & 15, q = lane >> 4;
  f32x4 acc[2][2] = {{{0.f,0.f,0.f,0.f},{0.f,0.f,0.f,0.f}},
                     {{0.f,0.f,0.f,0.f},{0.f,0.f,0.f,0.f}}};

  for (int k0 = 0; k0 < K; k0 += 64) {
    {
      const int kc = (tid & 7) * 8;
      const int r0 = tid >> 3;
      #pragma unroll
      for (int it = 0; it < 2; ++it) {
        const int row = r0 + 32*it;
        const size_t gmK = (size_t)(m0 + row) * (size_t)K;
        const int gk = k0 + kc;
        if constexpr (ABF16) {
          const u16* A16 = (const u16*)Ap;
          u16x8 u;
          if (gk + 7 < K) u = *(const u16x8*)(A16 + gmK + gk);
          else {
            #pragma unroll
            for (int e=0;e<8;e++) u[e] = (gk+e < K) ? A16[gmK + gk + e] : (u16)0;
          }
          *(u16x8*)&As[row*LDW + kc] = u;
        } else {
          const float* A32 = (const float*)Ap;
          float f[8];
          if (gk + 7 < K) {
            f32x4 va = *(const f32x4*)(A32 + gmK + gk);
            f32x4 vb = *(const f32x4*)(A32 + gmK + gk + 4);
            if constexpr (MIX) {
              f32x4 d0 = *(const f32x4*)(dxp + gmK + gk);
              f32x4 d1 = *(const f32x4*)(dxp + gmK + gk + 4);
              f32x4 c0 = *(const f32x4*)(mixp + gk);
              f32x4 c1 = *(const f32x4*)(mixp + gk + 4);
              va = va + d0*c0; vb = vb + d1*c1;
            }
            #pragma unroll
            for (int e=0;e<4;e++){ f[e]=va[e]; f[4+e]=vb[e]; }
          } else {
            #pragma unroll
            for (int e=0;e<8;e++){
              const int kk2 = gk+e;
              float xv = 0.f;
              if (kk2 < K) {
                xv = A32[gmK + kk2];
                if constexpr (MIX) xv = fmaf(dxp[gmK+kk2], mixp[kk2], xv);
              }
              f[e] = xv;
            }
          }
          bf16x8 v8;
          #pragma unroll
          for (int e=0;e<8;e++) v8[e] = (__bf16)f[e];
          *(bf16x8*)&As[row*LDW + kc] = v8;
        }
      }
    }
    if constexpr (WNK) {
      const int kc = (tid & 7) * 8;
      const int r0 = tid >> 3;
      #pragma unroll
      for (int it = 0; it < 2; ++it) {
        const int row = r0 + 32*it;
        const int gn = n0 + row;
        const int gk = k0 + kc;
        float f[8];
        if (gn < N && gk + 7 < K) {
          const size_t o = (size_t)gn * (size_t)K + gk;
          f32x4 va = *(const f32x4*)(Wp + o);
          f32x4 vb = *(const f32x4*)(Wp + o + 4);
          #pragma unroll
          for (int e=0;e<4;e++){ f[e]=va[e]; f[4+e]=vb[e]; }
        } else {
          #pragma unroll
          for (int e=0;e<8;e++) f[e] = (gn < N && gk+e < K) ? Wp[(size_t)gn*K + gk + e] : 0.f;
        }
        bf16x8 v8;
        #pragma unroll
        for (int e=0;e<8;e++) v8[e] = (__bf16)f[e];
        *(bf16x8*)&Bs[row*LDW + kc] = v8;
      }
    } else {
      const int nc = (tid & 15) * 4;
      const int kr = tid >> 4;
      #pragma unroll
      for (int it = 0; it < 4; ++it) {
        const int kk = kr + 16*it;
        const int gk = k0 + kk;
        f32x4 v = {0.f,0.f,0.f,0.f};
        if (gk < K) {
          const int gn = n0 + nc;
          if (gn + 3 < N) v = *(const f32x4*)(Wp + (size_t)gk*N + gn);
          else {
            #pragma unroll
            for (int e=0;e<4;e++) if (gn+e < N) v[e] = Wp[(size_t)gk*N + gn + e];
          }
        }
        #pragma unroll
        for (int e=0;e<4;e++) Bs[(nc+e)*LDW + kk] = (__bf16)v[e];
      }
    }
    __syncthreads();
    #pragma unroll
    for (int ks = 0; ks < 64; ks += 32) {
      bf16x8 af[2], bfv[2];
      #pragma unroll
      for (int i=0;i<2;i++) af[i]  = *(const bf16x8*)&As[(wm*32 + i*16 + l15)*LDW + ks + q*8];
      #pragma unroll
      for (int i=0;i<2;i++) bfv[i] = *(const bf16x8*)&Bs[(wn*32 + i*16 + l15)*LDW + ks + q*8];
      #pragma unroll
      for (int i=0;i<2;i++)
        #pragma unroll
        for (int j=0;j<2;j++)
          acc[i][j] = __builtin_amdgcn_mfma_f32_16x16x32_bf16(af[i], bfv[j], acc[i][j], 0, 0, 0);
    }
    __syncthreads();
  }
  #pragma unroll
  for (int i=0;i<2;i++) {
    #pragma unroll
    for (int j=0;j<2;j++) {
      #pragma unroll
      for (int rr=0;rr<4;rr++) {
        const int gm = m0 + wm*32 + i*16 + q*4 + rr;
        const int gn = n0 + wn*32 + j*16 + l15;
        if (gn < N) {
          const size_t o = (size_t)gm * (size_t)N + gn;
          const float a = acc[i][j][rr];
          if constexpr (EPI == 1) {
            float* C = (float*)Cp;
            const float s = sigm(mixp[gn] + a);
            const float vG = C[o];
            C[o] = vG + (dxp[o] - vG) * s;
          } else if constexpr (EPI == 2) {
            const float z = -(mixp[gn] + a);
            const float sp = (z > 20.f) ? z : log1pf(expf(z));
            ((float*)Cp)[o] = expf(-expf(-sp - 0.5f));
          } else if constexpr (EPI == 3) {
            ((u16*)Cp)[o] = f2bfu(sigm(mixp[gn] + a));
          } else if constexpr (EPI == 4) {
            ((u16*)Cp)[o] = f2bfu(tanhf(a));
          } else if constexpr (EPI == 5) {
            ((u16*)Cp)[o] = f2bfu(sigm(a));
          } else if constexpr (OBF16) {
            ((u16*)Cp)[o] = f2bfu(a);
          } else {
            ((float*)Cp)[o] = a;
          }
        }
      }
    }
  }
}

// ================= fused token-shift + 6-way mix + bf16 cast =================
__global__ void mix_cast_k(const float* __restrict__ x, const float* __restrict__ shift,
    const float* __restrict__ mr, const float* __restrict__ mw, const float* __restrict__ mk,
    const float* __restrict__ mv, const float* __restrict__ ma, const float* __restrict__ mg,
    u16* __restrict__ xr_b, u16* __restrict__ xw_b, u16* __restrict__ xk_b,
    u16* __restrict__ xv_b, u16* __restrict__ xa_b, u16* __restrict__ xg_b,
    float* __restrict__ xlast, int T_, int B_)
{
  const int Hh = 2048;
  size_t e4 = (size_t)blockIdx.x*blockDim.x + threadIdx.x;
  size_t total4 = (size_t)B_*T_*Hh/4;
  if (e4 >= total4) return;
  size_t e = e4*4;
  size_t th = (size_t)T_*Hh;
  size_t b = e / th; size_t rem = e - b*th;
  int t = (int)(rem / Hh); int c = (int)(rem & (Hh-1));
  f32x4 xv4 = *(const f32x4*)(x+e);
  f32x4 xp = t ? *(const f32x4*)(x+e-Hh) : *(const f32x4*)(shift + b*Hh + c);
  f32x4 dx = xp - xv4;
  if (t == T_-1) *(f32x4*)(xlast + b*Hh + c) = xv4;
  #define EMIT(mp, dst) { \
    f32x4 mc = *(const f32x4*)(mp + c); \
    f32x4 r_ = xv4 + dx*mc; \
    u16x4 o_; \
    o_[0]=f2bfu(r_[0]); o_[1]=f2bfu(r_[1]); o_[2]=f2bfu(r_[2]); o_[3]=f2bfu(r_[3]); \
    *(u16x4*)(dst + e) = o_; }
  EMIT(mr, xr_b) EMIT(mw, xw_b) EMIT(mk, xk_b)
  EMIT(mv, xv_b) EMIT(ma, xa_b) EMIT(mg, xg_b)
  #undef EMIT
}

// ================= weight f32 -> bf16 =================
__global__ void castw_k(const float* __restrict__ src, u16* __restrict__ dst, long n4){
  long i = (long)blockIdx.x*blockDim.x + threadIdx.x;
  if (i < n4) {
    f32x4 v = ((const f32x4*)src)[i];
    u16x4 o; o[0]=f2bfu(v[0]); o[1]=f2bfu(v[1]); o[2]=f2bfu(v[2]); o[3]=f2bfu(v[3]);
    ((u16x4*)dst)[i] = o;
  }
}

__global__ void copy4_k(float* __restrict__ dst, const float* __restrict__ src, long n4){
  long i = (long)blockIdx.x*blockDim.x + threadIdx.x;
  if (i < n4) ((f32x4*)dst)[i] = ((const f32x4*)src)[i];
}

// ================= r2 precompute: r2[b,t,h] = 1/max(||k*k_k||^2, 1e-24) =================
__global__ __launch_bounds__(256) void rnorm_k(
    const u16* __restrict__ kb, const float* __restrict__ kkw, float* __restrict__ r2)
{
  const size_t bt = blockIdx.x;
  const int tid = threadIdx.x;
  const int c0 = tid << 3;                      // 8 channels per thread
  u16x8 kv8 = *(const u16x8*)(kb + bt*2048 + c0);
  f32x4 ka_ = *(const f32x4*)(kkw + c0);
  f32x4 kb_ = *(const f32x4*)(kkw + c0 + 4);
  float s = 0.f;
  #pragma unroll
  for (int e=0;e<4;e++){ float kk = bfu2f(kv8[e])*ka_[e];   s = fmaf(kk,kk,s); }
  #pragma unroll
  for (int e=0;e<4;e++){ float kk = bfu2f(kv8[4+e])*kb_[e]; s = fmaf(kk,kk,s); }
  s += __shfl_xor(s, 1, 64);
  s += __shfl_xor(s, 2, 64);
  s += __shfl_xor(s, 4, 64);
  if ((tid & 7) == 0) r2[bt*32 + (tid>>3)] = 1.f/fmaxf(s, 1e-24f);
}

// ================= WKV scan (fallback, unchanged) =================
__global__ __launch_bounds__(64) __attribute__((amdgpu_waves_per_eu(1, 4)))
void scan_k(
    const u16* __restrict__ rb, const float* __restrict__ wb, const u16* __restrict__ kb,
    const float* __restrict__ vb, const u16* __restrict__ ab,
    const float* __restrict__ kkw, const float* __restrict__ kaw,
    const float* __restrict__ S0, float* __restrict__ yb, float* __restrict__ Sout, int T_)
{
  const int Hh = 2048, NHl = 32;
  const int blk = blockIdx.x;
  const int b = blk >> 5, h = blk & 31;
  const int lane = threadIdx.x;
  float S[64];
  const size_t sbase = (((size_t)b*NHl + h)*64 + lane)*64;
  #pragma unroll
  for (int i=0;i<64;i++) S[i] = S0[sbase+i];
  const float kkc = kkw[h*64+lane], kac = kaw[h*64+lane];
  __shared__ alignas(16) float lw[64], lkk[64], lka[64], lke[64], lr[64];
  size_t idx = (size_t)b*T_*Hh + (size_t)h*64 + lane;
  float rv = bfu2f(rb[idx]), wv = wb[idx], kv = bfu2f(kb[idx]), vv = vb[idx], av = bfu2f(ab[idx]);
  for (int t=0; t<T_; ++t) {
    float kk = kv * kkc;
    float ssum = kk*kk;
    #pragma unroll
    for (int m=1;m<64;m<<=1) ssum += __shfl_xor(ssum, m, 64);
    float inv = 1.f / fmaxf(sqrtf(ssum), 1e-12f);
    float kkn = kk * inv;
    float ke  = kv * (1.f + (av - 1.f)*kac);
    lw[lane]=wv; lkk[lane]=kkn; lka[lane]=kkn*av; lke[lane]=ke; lr[lane]=rv;
    const float vt = vv;
    __syncthreads();
    float nrv=0.f,nwv=0.f,nkv=0.f,nvv=0.f,nav=0.f;
    if (t+1 < T_) {
      const size_t ni = idx + Hh;
      nrv = bfu2f(rb[ni]); nwv = wb[ni]; nkv = bfu2f(kb[ni]); nvv = vb[ni]; nav = bfu2f(ab[ni]);
    }
    const f32x4* KK4 = (const f32x4*)lkk;
    const f32x4* W4  = (const f32x4*)lw;
    const f32x4* KA4 = (const f32x4*)lka;
    const f32x4* KE4 = (const f32x4*)lke;
    const f32x4* R4  = (const f32x4*)lr;
    float sa0=0.f,sa1=0.f,sa2=0.f,sa3=0.f;
    #pragma unroll
    for (int qq=0;qq<16;qq++){
      f32x4 k4 = KK4[qq];
      sa0 = fmaf(S[4*qq+0], k4[0], sa0);
      sa1 = fmaf(S[4*qq+1], k4[1], sa1);
      sa2 = fmaf(S[4*qq+2], k4[2], sa2);
      sa3 = fmaf(S[4*qq+3], k4[3], sa3);
    }
    const float sa = -((sa0+sa1)+(sa2+sa3));
    float y0=0.f,y1=0.f,y2=0.f,y3=0.f;
    #pragma unroll
    for (int qq=0;qq<16;qq++){
      f32x4 w4=W4[qq], a4=KA4[qq], e4=KE4[qq], r4=R4[qq];
      float s_;
      s_ = fmaf(vt, e4[0], fmaf(sa, a4[0], S[4*qq+0]*w4[0])); S[4*qq+0]=s_; y0 = fmaf(s_, r4[0], y0);
      s_ = fmaf(vt, e4[1], fmaf(sa, a4[1], S[4*qq+1]*w4[1])); S[4*qq+1]=s_; y1 = fmaf(s_, r4[1], y1);
      s_ = fmaf(vt, e4[2], fmaf(sa, a4[2], S[4*qq+2]*w4[2])); S[4*qq+2]=s_; y2 = fmaf(s_, r4[2], y2);
      s_ = fmaf(vt, e4[3], fmaf(sa, a4[3], S[4*qq+3]*w4[3])); S[4*qq+3]=s_; y3 = fmaf(s_, r4[3], y3);
    }
    yb[idx] = (y0+y1)+(y2+y3);
    __syncthreads();
    rv=nrv; wv=nwv; kv=nkv; vv=nvv; av=nav;
    idx += Hh;
  }
  #pragma unroll
  for (int i=0;i<64;i++) Sout[sbase+i] = S[i];
}

// ================= Phase A: key-split scan =================
// One WG = 128 threads = 2 waves = the two KEY-HALVES of one (chunk, role) unit.
// Wave phi owns S[v=lane][j in phi*32..phi*32+32) -> S[32] in regs (VGPR ~60,
// 7-8 waves/SIMD resident vs 5 before).  Per-step dot and y/d-dot become
// cross-wave sums via a tiny LDS exchange; 2 barriers/step between two
// symmetric lockstep waves.  Double-buffered LDS staging + register prefetch
// (R3/R4-proven).  Math identical to R4 modulo FP reassociation (64-sum ->
// two 32-sums).  Role 0 (M): S=I, no v; emits d_t -> Dbuf, P_64 -> Mbuf.
// Role 1 (U): S=0, full; emits ylocal_t -> yb, U_64 -> Ubuf.
__global__ __launch_bounds__(128, 7) void chunk_mu_k(
    const u16* __restrict__ rb, const float* __restrict__ wb, const u16* __restrict__ kb,
    const float* __restrict__ vb, const u16* __restrict__ ab,
    const float* __restrict__ kkw, const float* __restrict__ kaw,
    const float* __restrict__ r2b,
    float* __restrict__ Mbuf, float* __restrict__ Ubuf, float* __restrict__ Dbuf,
    float* __restrict__ yb, int T_, int NC)
{
  const int lane = threadIdx.x & 63;
  const int phi  = threadIdx.x >> 6;          // key half 0/1
  const int g    = blockIdx.x;                // unit = ch*2 + role
  const int ch   = g >> 1;
  const bool mrole = ((g & 1) == 0);
  const int c  = ch % NC;
  const int bh = ch / NC;
  const int b = bh >> 5, h = bh & 31;
  const int ulane = lane & 31;
  const bool stager = (lane < 32);
  const int mych = (phi << 5) + ulane;        // channel this lane stages

  float S[32];
  #pragma unroll
  for (int i=0;i<32;i++) S[i] = 0.f;
  if (mrole) {
    #pragma unroll
    for (int i=0;i<32;i++) if (lane == (phi<<5) + i) S[i] = 1.f;   // I, own columns
  }

  const int hcs = h*64 + mych;
  const float kkc = kkw[hcs], kac = kaw[hcs];  // used by stager lanes only

  __shared__ alignas(16) float LB[2][5][64];   // [buf][w,kk,ka,ke,r][chan]
  __shared__ alignas(16) float XC[2][64][2];   // [wave][lane][{saP, yP}]

  const size_t base = ((size_t)b*T_ + (size_t)c*64)*2048 + (size_t)h*64;
  const size_t r2i  = ((size_t)b*T_ + (size_t)c*64)*32 + h;
  float* dD = Dbuf + (size_t)ch*4096;

  // prologue: stage step 0 (each wave its 32 channels), prefetch step 1
  if (stager) {
    const size_t i0 = base + mych;
    const float kv = bfu2f(kb[i0]);
    const float av = bfu2f(ab[i0]);
    const float kk = kv*kkc;
    LB[0][0][mych] = wb[i0];
    LB[0][1][mych] = kk;
    LB[0][2][mych] = kk*av;
    LB[0][3][mych] = kv*(1.f+(av-1.f)*kac);
    LB[0][4][mych] = bfu2f(rb[i0]);
  }
  float c_vv = mrole ? 0.f : vb[base + lane];
  float c_r2 = r2b[r2i];
  float p_k=0.f,p_w=0.f,p_a=0.f,p_r=0.f,p_v=0.f,p_r2=0.f;
  {
    const size_t i1 = base + 2048;
    if (stager) {
      p_k = bfu2f(kb[i1+mych]); p_w = wb[i1+mych];
      p_a = bfu2f(ab[i1+mych]); p_r = bfu2f(rb[i1+mych]);
    }
    if (!mrole) p_v = vb[i1 + lane];
    p_r2 = r2b[r2i + 32];
  }
  __syncthreads();

  size_t yidx = base + lane;
  for (int j=0; j<64; ++j) {
    const int cur = j & 1;
    // 1. stage step j+1 into buf^1 (fenced by this step's barriers before read)
    if (j+1 < 64 && stager) {
      const float kk = p_k*kkc;
      LB[cur^1][0][mych] = p_w;
      LB[cur^1][1][mych] = kk;
      LB[cur^1][2][mych] = kk*p_a;
      LB[cur^1][3][mych] = p_k*(1.f+(p_a-1.f)*kac);
      LB[cur^1][4][mych] = p_r;
    }
    const float n_vv = p_v, n_r2 = p_r2;
    // 2. prefetch step j+2 into registers
    if (j+2 < 64) {
      const size_t i2 = base + (size_t)(j+2)*2048;
      if (stager) {
        p_k = bfu2f(kb[i2+mych]); p_w = wb[i2+mych];
        p_a = bfu2f(ab[i2+mych]); p_r = bfu2f(rb[i2+mych]);
      }
      if (!mrole) p_v = vb[i2 + lane];
      p_r2 = r2b[r2i + (size_t)(j+2)*32];
    }
    // 3. partial dot over own key half
    const f32x4* KK4 = (const f32x4*)&LB[cur][1][phi<<5];
    float s0=0.f,s1=0.f,s2=0.f,s3=0.f;
    #pragma unroll
    for (int qq=0;qq<8;qq++){
      f32x4 k4 = KK4[qq];
      s0 = fmaf(S[4*qq+0], k4[0], s0);
      s1 = fmaf(S[4*qq+1], k4[1], s1);
      s2 = fmaf(S[4*qq+2], k4[2], s2);
      s3 = fmaf(S[4*qq+3], k4[3], s3);
    }
    XC[phi][lane][0] = (s0+s1)+(s2+s3);
    __syncthreads();
    const float sa = -(XC[0][lane][0] + XC[1][lane][0]) * c_r2;
    const float vt = c_vv;
    // 4. update own half + partial output dot
    const f32x4* W4  = (const f32x4*)&LB[cur][0][phi<<5];
    const f32x4* KA4 = (const f32x4*)&LB[cur][2][phi<<5];
    const f32x4* KE4 = (const f32x4*)&LB[cur][3][phi<<5];
    const f32x4* R4  = (const f32x4*)&LB[cur][4][phi<<5];
    float y0=0.f,y1=0.f,y2=0.f,y3=0.f;
    if (mrole) {
      #pragma unroll
      for (int qq=0;qq<8;qq++){
        f32x4 w4=W4[qq], a4=KA4[qq], r4=R4[qq];
        float s_;
        s_ = fmaf(sa, a4[0], S[4*qq+0]*w4[0]); S[4*qq+0]=s_; y0 = fmaf(s_, r4[0], y0);
        s_ = fmaf(sa, a4[1], S[4*qq+1]*w4[1]); S[4*qq+1]=s_; y1 = fmaf(s_, r4[1], y1);
        s_ = fmaf(sa, a4[2], S[4*qq+2]*w4[2]); S[4*qq+2]=s_; y2 = fmaf(s_, r4[2], y2);
        s_ = fmaf(sa, a4[3], S[4*qq+3]*w4[3]); S[4*qq+3]=s_; y3 = fmaf(s_, r4[3], y3);
      }
    } else {
      #pragma unroll
      for (int qq=0;qq<8;qq++){
        f32x4 w4=W4[qq], a4=KA4[qq], e4=KE4[qq], r4=R4[qq];
        float s_;
        s_ = fmaf(vt, e4[0], fmaf(sa, a4[0], S[4*qq+0]*w4[0])); S[4*qq+0]=s_; y0 = fmaf(s_, r4[0], y0);
        s_ = fmaf(vt, e4[1], fmaf(sa, a4[1], S[4*qq+1]*w4[1])); S[4*qq+1]=s_; y1 = fmaf(s_, r4[1], y1);
        s_ = fmaf(vt, e4[2], fmaf(sa, a4[2], S[4*qq+2]*w4[2])); S[4*qq+2]=s_; y2 = fmaf(s_, r4[2], y2);
        s_ = fmaf(vt, e4[3], fmaf(sa, a4[3], S[4*qq+3]*w4[3])); S[4*qq+3]=s_; y3 = fmaf(s_, r4[3], y3);
      }
    }
    XC[phi][lane][1] = (y0+y1)+(y2+y3);
    __syncthreads();
    if (phi == (j & 1)) {                       // alternate which wave stores
      const float yv = XC[0][lane][1] + XC[1][lane][1];
      if (mrole) dD[(size_t)j*64 + lane] = yv;  // d_t[lane]
      else       yb[yidx] = yv;                 // ylocal_t[lane]
    }
    c_vv = n_vv; c_r2 = n_r2;
    yidx += 2048;
  }
  // final state: each wave stores its 32 columns of every row
  float* fd = (mrole ? Mbuf : Ubuf) + (size_t)ch*4096 + (size_t)lane*64 + (phi<<5);
  #pragma unroll
  for (int qq=0;qq<8;qq++)
    *(f32x4*)(fd + 4*qq) = f32x4{S[4*qq+0],S[4*qq+1],S[4*qq+2],S[4*qq+3]};
}

// ================= Phase B: sequential inter-chunk state propagation =================
// NOTE: SSbuf aliases Ubuf (SS overlays U).  Each thread loads its U element
// BEFORE storing SS to the same address (same-thread same-address -> ordered),
// so no __restrict__ on these two params.
__global__ __launch_bounds__(256) void propagate_k(
    const float* __restrict__ Mbuf, const float* Ubuf,
    const float* __restrict__ S0, float* SSbuf, float* __restrict__ Sout, int NC)
{
  const int bh   = blockIdx.x >> 2;
  const int v0r  = (blockIdx.x & 3) * 16;
  const int tid  = threadIdx.x;
  const int lane = tid & 63;
  const int wvv  = tid >> 6;

  __shared__ float MT[64*65];
  __shared__ float Srow[16][64];

  #pragma unroll
  for (int i=0;i<4;i++) {
    const int v = v0r + wvv*4 + i;
    Srow[wvv*4+i][lane] = S0[((size_t)bh*64 + v)*64 + lane];
  }

  const size_t mbase = (size_t)bh * NC * 4096;
  f32x4 mreg[4];
  #pragma unroll
  for (int it=0; it<4; ++it)
    mreg[it] = *(const f32x4*)(Mbuf + mbase + it*1024 + tid*4);

  for (int c=0; c<NC; ++c) {
    const size_t chB = mbase + (size_t)c*4096;
    #pragma unroll
    for (int it=0; it<4; ++it) {
      const int base = it*1024 + tid*4;
      const int j = base >> 6;
      const int k = base & 63;
      #pragma unroll
      for (int e=0;e<4;e++) MT[(k+e)*65 + j] = mreg[it][e];
    }
    __syncthreads();
    if (c+1 < NC) {
      #pragma unroll
      for (int it=0; it<4; ++it)
        mreg[it] = *(const f32x4*)(Mbuf + chB + 4096 + it*1024 + tid*4);
    }
    float u[4];
    #pragma unroll
    for (int i=0;i<4;i++)
      u[i] = Ubuf[chB + (size_t)(v0r + wvv*4 + i)*64 + lane];
    #pragma unroll
    for (int i=0;i<4;i++)
      SSbuf[chB + (size_t)(v0r + wvv*4 + i)*64 + lane] = Srow[wvv*4+i][lane];
    float acc[4] = {0.f,0.f,0.f,0.f};
    #pragma unroll
    for (int j4=0; j4<16; ++j4) {
      float m0_ = MT[lane*65 + j4*4 + 0];
      float m1_ = MT[lane*65 + j4*4 + 1];
      float m2_ = MT[lane*65 + j4*4 + 2];
      float m3_ = MT[lane*65 + j4*4 + 3];
      #pragma unroll
      for (int i=0;i<4;i++) {
        f32x4 s4 = *(const f32x4*)&Srow[wvv*4+i][j4*4];
        acc[i] = fmaf(s4[0], m0_, acc[i]);
        acc[i] = fmaf(s4[1], m1_, acc[i]);
        acc[i] = fmaf(s4[2], m2_, acc[i]);
        acc[i] = fmaf(s4[3], m3_, acc[i]);
      }
    }
    #pragma unroll
    for (int i=0;i<4;i++) Srow[wvv*4+i][lane] = acc[i] + u[i];
    __syncthreads();
  }
  #pragma unroll
  for (int i=0;i<4;i++) {
    const int v = v0r + wvv*4 + i;
    Sout[((size_t)bh*64 + v)*64 + lane] = Srow[wvv*4+i][lane];
  }
}

// ================= Phase C: y correction  y[t][v] += sum_j SS[v][j] * D[t][j] ==========
// 4-wave WG per chunk-head: SS and D staged once cooperatively; each wave
// handles 16 t-rows (no 64-long serial loop, 4x the wave count of the old
// 1-wave version).  D rows read at wave-uniform addresses -> conflict-free.
__global__ __launch_bounds__(256) void ycorr_k(
    const float* __restrict__ SSbuf, const float* __restrict__ Dbuf,
    float* __restrict__ yb, int T_, int NC)
{
  const int ch = blockIdx.x;
  const int c  = ch % NC;
  const int bh = ch / NC;
  const int b = bh >> 5, h = bh & 31;
  const int tid = threadIdx.x;
  const int wid = tid >> 6, lane = tid & 63;

  __shared__ alignas(16) float Sl[64*68];
  __shared__ alignas(16) float Dl[64*68];

  {
    const float* sg = SSbuf + (size_t)ch*4096;
    const float* dg = Dbuf  + (size_t)ch*4096;
    #pragma unroll
    for (int i=0;i<4;i++){
      const int o = i*1024 + tid*4;
      f32x4 vs = *(const f32x4*)(sg + o);
      f32x4 vd = *(const f32x4*)(dg + o);
      const int rr = o >> 6, cc = o & 63;
      *(f32x4*)&Sl[rr*68 + cc] = vs;
      *(f32x4*)&Dl[rr*68 + cc] = vd;
    }
  }
  __syncthreads();
  float ss[64];
  #pragma unroll
  for (int qq=0;qq<16;qq++){
    f32x4 v = *(const f32x4*)&Sl[lane*68 + 4*qq];
    ss[4*qq+0]=v[0]; ss[4*qq+1]=v[1]; ss[4*qq+2]=v[2]; ss[4*qq+3]=v[3];
  }
  size_t idx = ((size_t)b*T_ + (size_t)c*64 + (size_t)wid*16)*2048 + (size_t)h*64 + lane;
  for (int tt=0; tt<16; ++tt) {
    const f32x4* D4 = (const f32x4*)&Dl[(wid*16 + tt)*68];
    float a0=0.f,a1=0.f,a2=0.f,a3=0.f;
    #pragma unroll
    for (int qq=0;qq<16;qq++){
      f32x4 d4 = D4[qq];
      a0 = fmaf(ss[4*qq+0], d4[0], a0);
      a1 = fmaf(ss[4*qq+1], d4[1], a1);
      a2 = fmaf(ss[4*qq+2], d4[2], a2);
      a3 = fmaf(ss[4*qq+3], d4[3], a3);
    }
    yb[idx] = yb[idx] + ((a0+a1)+(a2+a3));
    idx += 2048;
  }
}

// ================= post: groupnorm + rk*v + gate -> bf16 z =================
__global__ __launch_bounds__(256) void post_k(
    const float* __restrict__ yb, const u16* __restrict__ rb, const u16* __restrict__ kb,
    const u16* __restrict__ ab, const u16* __restrict__ gb, const float* __restrict__ vb,
    const float* __restrict__ kaw, const float* __restrict__ rkw,
    const float* __restrict__ lnw, const float* __restrict__ lnb, u16* __restrict__ zb)
{
  const int wid = threadIdx.x >> 6, lane = threadIdx.x & 63;
  const size_t unit = (size_t)blockIdx.x*4 + wid;
  const size_t bt = unit >> 5; const int h = (int)(unit & 31);
  const size_t idx = bt*2048 + (size_t)h*64 + lane;
  const int hc = h*64 + lane;
  const float yv = yb[idx];
  const float rv = bfu2f(rb[idx]), kv = bfu2f(kb[idx]), av = bfu2f(ab[idx]);
  const float ke = kv*(1.f + (av-1.f)*kaw[hc]);
  float s1 = yv, s2 = yv*yv, rk = rv*ke*rkw[hc];
  #pragma unroll
  for (int m=1;m<64;m<<=1){
    s1 += __shfl_xor(s1,m,64);
    s2 += __shfl_xor(s2,m,64);
    rk += __shfl_xor(rk,m,64);
  }
  const float mean = s1 * (1.f/64.f);
  const float var  = s2 * (1.f/64.f) - mean*mean;
  const float rstd = rsqrtf(var + 6.4e-4f);
  const float zn = (yv-mean)*rstd*lnw[hc] + lnb[hc] + rk*vb[idx];
  zb[idx] = f2bfu(zn * bfu2f(gb[idx]));
}

// ================= host =================
extern "C" void kernel_launch(void* const* d_in, const int* in_sizes, int n_in,
                              void* d_out, int out_size, void* d_ws, size_t ws_size,
                              hipStream_t stream)
{
  const float* x      = (const float*)d_in[0];
  const float* shift  = (const float*)d_in[1];
  const float* wkv0   = (const float*)d_in[2];
  const float* vfirst = (const float*)d_in[3];
  const float* xr = (const float*)d_in[4];
  const float* xw = (const float*)d_in[5];
  const float* xk = (const float*)d_in[6];
  const float* xv = (const float*)d_in[7];
  const float* xa = (const float*)d_in[8];
  const float* xg = (const float*)d_in[9];
  const float* w0 = (const float*)d_in[10];
  const float* w1 = (const float*)d_in[11];
  const float* w2 = (const float*)d_in[12];
  const float* a0 = (const float*)d_in[13];
  const float* a1 = (const float*)d_in[14];
  const float* a2 = (const float*)d_in[15];
  const float* v0 = (const float*)d_in[16];
  const float* v1 = (const float*)d_in[17];
  const float* v2 = (const float*)d_in[18];
  const float* g1 = (const float*)d_in[19];
  const float* g2 = (const float*)d_in[20];
  const float* k_k = (const float*)d_in[21];
  const float* k_a = (const float*)d_in[22];
  const float* r_k = (const float*)d_in[23];
  const float* W_r = (const float*)d_in[24];
  const float* W_k = (const float*)d_in[25];
  const float* W_v = (const float*)d_in[26];
  const float* W_o = (const float*)d_in[27];
  const float* ln_w = (const float*)d_in[28];
  const float* ln_b = (const float*)d_in[29];

  const int H = 2048, NH = 32;
  const int BH = in_sizes[1];
  const int B  = BH / H;
  const long BTH = (long)in_sizes[0];
  const int T  = (int)(BTH / BH);
  const int M  = (int)(BTH / H);

  float* out0 = (float*)d_out;
  float* out1 = out0 + BTH;
  float* out2 = out1 + BH;
  float* out3 = out2 + (size_t)B*NH*64*64;

  // ---- workspace layout (unchanged total) ----
  char* ws = (char*)d_ws;
  u16* mixb = (u16*)ws;  ws += (size_t)BTH*12;   // region A: 6 bf16 mixed bufs
  u16* xr_b = mixb + 0*BTH;
  u16* xw_b = mixb + 1*BTH;
  u16* xk_b = mixb + 2*BTH;
  u16* xv_b = mixb + 3*BTH;
  u16* xa_b = mixb + 4*BTH;
  u16* xg_b = mixb + 5*BTH;
  // region A reuse (mixed bufs dead after big GEMMs):
  //   phase A writes M, U, D;  propagate overlays SS onto U (U read-then-write,
  //   same thread+address);  phase C reads SS(=U region) + D;  post overlays zb16
  //   onto the M region (M dead after propagate).
  float* Mbuf  = (float*)mixb;           // BTH f32
  float* Ubuf  = Mbuf + BTH;
  float* Dbuf  = Ubuf + BTH;
  float* SSbuf = Ubuf;                   // alias: SS overlays U
  u16*   zb16  = (u16*)mixb;             // post phase
  u16* rb   = (u16*)ws;  ws += BTH*2;
  u16* kb   = (u16*)ws;  ws += BTH*2;
  u16* ab   = (u16*)ws;  ws += BTH*2;
  u16* gb   = (u16*)ws;  ws += BTH*2;
  u16* wr16 = (u16*)ws;  ws += (size_t)H*H*2;
  u16* wk16 = (u16*)ws;  ws += (size_t)H*H*2;
  u16* wv16 = (u16*)ws;  ws += (size_t)H*H*2;
  u16* wo16 = (u16*)ws;  ws += (size_t)H*H*2;
  u16* h1w  = (u16*)ws;  ws += (size_t)M*96*2;
  u16* h1a  = (u16*)ws;  ws += (size_t)M*96*2;
  u16* h1v  = (u16*)ws;  ws += (size_t)M*64*2;
  u16* h1g  = (u16*)ws;  ws += (size_t)M*256*2;
  float* dxz = (float*)ws; ws += BTH*4;          // w_raw -> w (f32)
  float* r2b = (float*)h1w;                      // M*NH*4 = 1 MB <= M*96*2; h1w dead after w2 gemm
  const size_t ws_need = (size_t)(ws - (char*)d_ws);
  const bool chunked = (ws_size >= ws_need) && (T % 64 == 0);
  const bool big_ok  = (M % 128 == 0);           // H==2048 always ok
  (void)n_in; (void)out_size;

  const dim3 blk(256);
  auto gg  = [&](int N){ return dim3(M/64, (N+63)/64); };
  auto gg128 = [&](int N){ return dim3(M/128, N/128); };

  // 1. fused token-shift + 6-way mix + bf16 cast; out1 = x[:,-1]
  mix_cast_k<<<dim3((unsigned)((BTH/4 + 255)/256)), blk, 0, stream>>>(
      x, shift, xr, xw, xk, xv, xa, xg, xr_b, xw_b, xk_b, xv_b, xa_b, xg_b, out1, T, B);

  // 2. weights -> bf16
  {
    const long n4 = (long)H*H/4;
    const dim3 gw((unsigned)((n4 + 255)/256));
    castw_k<<<gw, blk, 0, stream>>>(W_r, wr16, n4);
    castw_k<<<gw, blk, 0, stream>>>(W_k, wk16, n4);
    castw_k<<<gw, blk, 0, stream>>>(W_v, wv16, n4);
    castw_k<<<gw, blk, 0, stream>>>(W_o, wo16, n4);
  }

  // 3. stage-1 LoRA projections (bf16 A); tanh fused into w1, sigmoid into g1
  gemm_k<false,false,true,true,4><<<gg(96),  blk, 0, stream>>>(xw_b, nullptr, nullptr, w1, h1w, M, 96,  H);
  gemm_k<false,false,true,true  ><<<gg(96),  blk, 0, stream>>>(xa_b, nullptr, nullptr, a1, h1a, M, 96,  H);
  gemm_k<false,false,true,true  ><<<gg(64),  blk, 0, stream>>>(xv_b, nullptr, nullptr, v1, h1v, M, 64,  H);
  gemm_k<false,false,true,true,5><<<gg(256), blk, 0, stream>>>(xg_b, nullptr, nullptr, g1, h1g, M, 256, H);

  // 4. big projections (bf16 x bf16)
  if (big_ok) {
    gemm128_k<true ><<<gg128(H), blk, 0, stream>>>(xr_b, wr16, rb,   M, H, H);
    gemm128_k<true ><<<gg128(H), blk, 0, stream>>>(xk_b, wk16, kb,   M, H, H);
    gemm128_k<false><<<gg128(H), blk, 0, stream>>>(xv_b, wv16, out3, M, H, H);
  } else {
    gemm_k<false,true,true,true ><<<gg(H), blk, 0, stream>>>(xr_b, nullptr, nullptr, W_r, rb,   M, H, H);
    gemm_k<false,true,true,true ><<<gg(H), blk, 0, stream>>>(xk_b, nullptr, nullptr, W_k, kb,   M, H, H);
    gemm_k<false,true,true,false><<<gg(H), blk, 0, stream>>>(xv_b, nullptr, nullptr, W_v, out3, M, H, H);
  }

  // 5. stage-2 LoRA projections; w-transform fused into w2, a-sigmoid into a2,
  //    v-blend into v2 epilogue
  gemm_k<false,false,true,false,2><<<gg(H), blk, 0, stream>>>(h1w, nullptr, w0, w2, dxz, M, H, 96);
  // h1w dead from here -> r2b overlay becomes live; kb ready since step 4
  rnorm_k<<<dim3((unsigned)M), blk, 0, stream>>>(kb, k_k, r2b);
  gemm_k<false,false,true,true,3 ><<<gg(H), blk, 0, stream>>>(h1a, nullptr, a0, a2, ab,  M, H, 96);
  gemm_k<false,false,true,false,1><<<gg(H), blk, 0, stream>>>(h1v, vfirst,  v0, v2, out3, M, H, 64);
  gemm_k<false,false,true,true   ><<<gg(H), blk, 0, stream>>>(h1g, nullptr, nullptr, g2, gb,  M, H, 256);

  // 6. chunked WKV: phase A (M+D, U+ylocal; key-split 2-wave WGs) -> propagate -> ycorr
  if (chunked) {
    const int NC = T / 64;
    const int CH = B * NH * NC;
    chunk_mu_k <<<dim3((unsigned)(2*CH)), dim3(128), 0, stream>>>(rb, dxz, kb, out3, ab, k_k, k_a, r2b,
                                                                  Mbuf, Ubuf, Dbuf, out0, T, NC);
    propagate_k<<<dim3(B*NH*4), blk,      0, stream>>>(Mbuf, Ubuf, wkv0, SSbuf, out2, NC);
    ycorr_k    <<<dim3(CH),     blk,      0, stream>>>(SSbuf, Dbuf, out0, T, NC);
  } else {
    scan_k<<<dim3(B*NH), dim3(64), 0, stream>>>(rb, dxz, kb, out3, ab, k_k, k_a, wkv0, out0, out2, T);
  }

  // 7. groupnorm + rk*v + gate -> bf16 z (overlays dead Mbuf)
  post_k<<<dim3((unsigned)((size_t)M*NH/4)), blk, 0, stream>>>(out0, rb, kb, ab, gb, out3,
                                                               k_a, r_k, ln_w, ln_b, zb16);

  // 8. v_first passthrough (v in out3 dead after post)
  copy4_k<<<dim3((unsigned)((BTH/4 + 255)/256)), blk, 0, stream>>>(out3, vfirst, BTH/4);

  // 9. out = z @ W_o.T
  if (big_ok) {
    gemm128_k<false><<<gg128(H), blk, 0, stream>>>(zb16, wo16, out0, M, H, H);
  } else {
    gemm_k<false,true,true,false><<<gg(H), blk, 0, stream>>>(zb16, nullptr, nullptr, W_o, out0, M, H, H);
  }
}

// Round 6
// 1848.589 us; speedup vs baseline: 1.9867x; 1.9867x over previous
//
#include <hip/hip_runtime.h>

typedef unsigned short u16;
typedef __attribute__((ext_vector_type(4))) float f32x4;
typedef __attribute__((ext_vector_type(8))) __bf16 bf16x8;
typedef __attribute__((ext_vector_type(8))) unsigned short u16x8;
typedef __attribute__((ext_vector_type(4))) unsigned short u16x4;

#define DI static __device__ __forceinline__

DI float bfu2f(u16 u){ unsigned int x = ((unsigned int)u)<<16; float f; __builtin_memcpy(&f,&x,4); return f; }
DI u16 f2bfu(float f){ __bf16 h = (__bf16)f; u16 u; __builtin_memcpy(&u,&h,2); return u; }
DI float sigm(float x){ return 1.f/(1.f+expf(-x)); }

DI void gload_lds16(const void* g, void* l) {
  __builtin_amdgcn_global_load_lds(
      (const __attribute__((address_space(1))) unsigned int*)g,
      (__attribute__((address_space(3))) unsigned int*)l, 16, 0, 0);
}

// ================= big GEMM: 128x128 tile, global_load_lds staging =================
// C[M,N] = A[M,K](bf16) @ Bt[N,K](bf16)^T.  Requires M%128==0, N%128==0, K%64==0.
template<bool OBF16>
__global__ __launch_bounds__(256) void gemm128_k(
    const u16* __restrict__ A, const u16* __restrict__ Bt,
    void* __restrict__ Cp, int M, int N, int K)
{
  __shared__ alignas(16) u16 As[128*64];
  __shared__ alignas(16) u16 Bs[128*64];
  const int tid = threadIdx.x;
  const int wid = tid >> 6, lane = tid & 63;
  const int wm = wid >> 1, wn = wid & 1;
  const int l15 = lane & 15, q = lane >> 4;
  const int m0 = blockIdx.x * 128, n0 = blockIdx.y * 128;
  const int sr = (wid << 3) + (lane >> 3);   // staging row within 32-row round
  const int sc = (lane & 7) << 3;            // staging col (bf16 elems)
  f32x4 acc[4][4];
  #pragma unroll
  for (int i=0;i<4;i++)
    #pragma unroll
    for (int j=0;j<4;j++) acc[i][j] = f32x4{0.f,0.f,0.f,0.f};

  char* la = (char*)As + (size_t)wid*1024;
  char* lb = (char*)Bs + (size_t)wid*1024;
  for (int k0 = 0; k0 < K; k0 += 64) {
    const u16* ga = A  + (size_t)(m0 + sr)*K + k0 + sc;
    const u16* gb = Bt + (size_t)(n0 + sr)*K + k0 + sc;
    #pragma unroll
    for (int it = 0; it < 4; ++it) {
      gload_lds16(ga + (size_t)(32*it)*K, la + it*4096);
      gload_lds16(gb + (size_t)(32*it)*K, lb + it*4096);
    }
    __syncthreads();
    #pragma unroll
    for (int ks = 0; ks < 64; ks += 32) {
      bf16x8 af[4], bfv[4];
      #pragma unroll
      for (int i=0;i<4;i++) af[i]  = *(const bf16x8*)&As[(wm*64 + i*16 + l15)*64 + ks + q*8];
      #pragma unroll
      for (int j=0;j<4;j++) bfv[j] = *(const bf16x8*)&Bs[(wn*64 + j*16 + l15)*64 + ks + q*8];
      #pragma unroll
      for (int i=0;i<4;i++)
        #pragma unroll
        for (int j=0;j<4;j++)
          acc[i][j] = __builtin_amdgcn_mfma_f32_16x16x32_bf16(af[i], bfv[j], acc[i][j], 0, 0, 0);
    }
    __syncthreads();
  }
  // C/D map: row=(lane>>4)*4+reg, col=lane&15  [m89-verified]
  #pragma unroll
  for (int i=0;i<4;i++)
    #pragma unroll
    for (int j=0;j<4;j++)
      #pragma unroll
      for (int rr=0;rr<4;rr++) {
        const int gm = m0 + wm*64 + i*16 + q*4 + rr;
        const int gn = n0 + wn*64 + j*16 + l15;
        const size_t o = (size_t)gm * (size_t)N + gn;
        if constexpr (OBF16) ((u16*)Cp)[o] = f2bfu(acc[i][j][rr]);
        else                 ((float*)Cp)[o] = acc[i][j][rr];
      }
}

// ================= small GEMM (64x64 tile) =================
// EPI: 0 none; 1 v-blend (dxp=vfirst, mixp=v0, Cp f32 RMW);
//      2 w-transform (mixp=w0, f32 out); 3 a-sigmoid (mixp=a0, bf16 out);
//      4 tanh (bf16 out); 5 sigmoid (bf16 out)
constexpr int LDW = 72;

template<bool MIX, bool WNK, bool ABF16, bool OBF16, int EPI=0>
__global__ __launch_bounds__(256) void gemm_k(
    const void* __restrict__ Ap, const float* __restrict__ dxp, const float* __restrict__ mixp,
    const float* __restrict__ Wp, void* __restrict__ Cp, int M, int N, int K)
{
  __shared__ alignas(16) __bf16 As[64*LDW];
  __shared__ alignas(16) __bf16 Bs[64*LDW];
  const int tid = threadIdx.x;
  const int m0 = blockIdx.x * 64;
  const int n0 = blockIdx.y * 64;
  const int lane = tid & 63, wid = tid >> 6;
  const int wm = wid >> 1, wn = wid & 1;
  const int l15 = lane & 15, q = lane >> 4;
  f32x4 acc[2][2] = {{{0.f,0.f,0.f,0.f},{0.f,0.f,0.f,0.f}},
                     {{0.f,0.f,0.f,0.f},{0.f,0.f,0.f,0.f}}};

  for (int k0 = 0; k0 < K; k0 += 64) {
    {
      const int kc = (tid & 7) * 8;
      const int r0 = tid >> 3;
      #pragma unroll
      for (int it = 0; it < 2; ++it) {
        const int row = r0 + 32*it;
        const size_t gmK = (size_t)(m0 + row) * (size_t)K;
        const int gk = k0 + kc;
        if constexpr (ABF16) {
          const u16* A16 = (const u16*)Ap;
          u16x8 u;
          if (gk + 7 < K) u = *(const u16x8*)(A16 + gmK + gk);
          else {
            #pragma unroll
            for (int e=0;e<8;e++) u[e] = (gk+e < K) ? A16[gmK + gk + e] : (u16)0;
          }
          *(u16x8*)&As[row*LDW + kc] = u;
        } else {
          const float* A32 = (const float*)Ap;
          float f[8];
          if (gk + 7 < K) {
            f32x4 va = *(const f32x4*)(A32 + gmK + gk);
            f32x4 vb = *(const f32x4*)(A32 + gmK + gk + 4);
            if constexpr (MIX) {
              f32x4 d0 = *(const f32x4*)(dxp + gmK + gk);
              f32x4 d1 = *(const f32x4*)(dxp + gmK + gk + 4);
              f32x4 c0 = *(const f32x4*)(mixp + gk);
              f32x4 c1 = *(const f32x4*)(mixp + gk + 4);
              va = va + d0*c0; vb = vb + d1*c1;
            }
            #pragma unroll
            for (int e=0;e<4;e++){ f[e]=va[e]; f[4+e]=vb[e]; }
          } else {
            #pragma unroll
            for (int e=0;e<8;e++){
              const int kk2 = gk+e;
              float xv = 0.f;
              if (kk2 < K) {
                xv = A32[gmK + kk2];
                if constexpr (MIX) xv = fmaf(dxp[gmK+kk2], mixp[kk2], xv);
              }
              f[e] = xv;
            }
          }
          bf16x8 v8;
          #pragma unroll
          for (int e=0;e<8;e++) v8[e] = (__bf16)f[e];
          *(bf16x8*)&As[row*LDW + kc] = v8;
        }
      }
    }
    if constexpr (WNK) {
      const int kc = (tid & 7) * 8;
      const int r0 = tid >> 3;
      #pragma unroll
      for (int it = 0; it < 2; ++it) {
        const int row = r0 + 32*it;
        const int gn = n0 + row;
        const int gk = k0 + kc;
        float f[8];
        if (gn < N && gk + 7 < K) {
          const size_t o = (size_t)gn * (size_t)K + gk;
          f32x4 va = *(const f32x4*)(Wp + o);
          f32x4 vb = *(const f32x4*)(Wp + o + 4);
          #pragma unroll
          for (int e=0;e<4;e++){ f[e]=va[e]; f[4+e]=vb[e]; }
        } else {
          #pragma unroll
          for (int e=0;e<8;e++) f[e] = (gn < N && gk+e < K) ? Wp[(size_t)gn*K + gk + e] : 0.f;
        }
        bf16x8 v8;
        #pragma unroll
        for (int e=0;e<8;e++) v8[e] = (__bf16)f[e];
        *(bf16x8*)&Bs[row*LDW + kc] = v8;
      }
    } else {
      const int nc = (tid & 15) * 4;
      const int kr = tid >> 4;
      #pragma unroll
      for (int it = 0; it < 4; ++it) {
        const int kk = kr + 16*it;
        const int gk = k0 + kk;
        f32x4 v = {0.f,0.f,0.f,0.f};
        if (gk < K) {
          const int gn = n0 + nc;
          if (gn + 3 < N) v = *(const f32x4*)(Wp + (size_t)gk*N + gn);
          else {
            #pragma unroll
            for (int e=0;e<4;e++) if (gn+e < N) v[e] = Wp[(size_t)gk*N + gn + e];
          }
        }
        #pragma unroll
        for (int e=0;e<4;e++) Bs[(nc+e)*LDW + kk] = (__bf16)v[e];
      }
    }
    __syncthreads();
    #pragma unroll
    for (int ks = 0; ks < 64; ks += 32) {
      bf16x8 af[2], bfv[2];
      #pragma unroll
      for (int i=0;i<2;i++) af[i]  = *(const bf16x8*)&As[(wm*32 + i*16 + l15)*LDW + ks + q*8];
      #pragma unroll
      for (int i=0;i<2;i++) bfv[i] = *(const bf16x8*)&Bs[(wn*32 + i*16 + l15)*LDW + ks + q*8];
      #pragma unroll
      for (int i=0;i<2;i++)
        #pragma unroll
        for (int j=0;j<2;j++)
          acc[i][j] = __builtin_amdgcn_mfma_f32_16x16x32_bf16(af[i], bfv[j], acc[i][j], 0, 0, 0);
    }
    __syncthreads();
  }
  #pragma unroll
  for (int i=0;i<2;i++) {
    #pragma unroll
    for (int j=0;j<2;j++) {
      #pragma unroll
      for (int rr=0;rr<4;rr++) {
        const int gm = m0 + wm*32 + i*16 + q*4 + rr;
        const int gn = n0 + wn*32 + j*16 + l15;
        if (gn < N) {
          const size_t o = (size_t)gm * (size_t)N + gn;
          const float a = acc[i][j][rr];
          if constexpr (EPI == 1) {
            float* C = (float*)Cp;
            const float s = sigm(mixp[gn] + a);
            const float vG = C[o];
            C[o] = vG + (dxp[o] - vG) * s;
          } else if constexpr (EPI == 2) {
            const float z = -(mixp[gn] + a);
            const float sp = (z > 20.f) ? z : log1pf(expf(z));
            ((float*)Cp)[o] = expf(-expf(-sp - 0.5f));
          } else if constexpr (EPI == 3) {
            ((u16*)Cp)[o] = f2bfu(sigm(mixp[gn] + a));
          } else if constexpr (EPI == 4) {
            ((u16*)Cp)[o] = f2bfu(tanhf(a));
          } else if constexpr (EPI == 5) {
            ((u16*)Cp)[o] = f2bfu(sigm(a));
          } else if constexpr (OBF16) {
            ((u16*)Cp)[o] = f2bfu(a);
          } else {
            ((float*)Cp)[o] = a;
          }
        }
      }
    }
  }
}

// ================= fused token-shift + 6-way mix + bf16 cast =================
__global__ void mix_cast_k(const float* __restrict__ x, const float* __restrict__ shift,
    const float* __restrict__ mr, const float* __restrict__ mw, const float* __restrict__ mk,
    const float* __restrict__ mv, const float* __restrict__ ma, const float* __restrict__ mg,
    u16* __restrict__ xr_b, u16* __restrict__ xw_b, u16* __restrict__ xk_b,
    u16* __restrict__ xv_b, u16* __restrict__ xa_b, u16* __restrict__ xg_b,
    float* __restrict__ xlast, int T_, int B_)
{
  const int Hh = 2048;
  size_t e4 = (size_t)blockIdx.x*blockDim.x + threadIdx.x;
  size_t total4 = (size_t)B_*T_*Hh/4;
  if (e4 >= total4) return;
  size_t e = e4*4;
  size_t th = (size_t)T_*Hh;
  size_t b = e / th; size_t rem = e - b*th;
  int t = (int)(rem / Hh); int c = (int)(rem & (Hh-1));
  f32x4 xv4 = *(const f32x4*)(x+e);
  f32x4 xp = t ? *(const f32x4*)(x+e-Hh) : *(const f32x4*)(shift + b*Hh + c);
  f32x4 dx = xp - xv4;
  if (t == T_-1) *(f32x4*)(xlast + b*Hh + c) = xv4;
  #define EMIT(mp, dst) { \
    f32x4 mc = *(const f32x4*)(mp + c); \
    f32x4 r_ = xv4 + dx*mc; \
    u16x4 o_; \
    o_[0]=f2bfu(r_[0]); o_[1]=f2bfu(r_[1]); o_[2]=f2bfu(r_[2]); o_[3]=f2bfu(r_[3]); \
    *(u16x4*)(dst + e) = o_; }
  EMIT(mr, xr_b) EMIT(mw, xw_b) EMIT(mk, xk_b)
  EMIT(mv, xv_b) EMIT(ma, xa_b) EMIT(mg, xg_b)
  #undef EMIT
}

// ================= weight f32 -> bf16 =================
__global__ void castw_k(const float* __restrict__ src, u16* __restrict__ dst, long n4){
  long i = (long)blockIdx.x*blockDim.x + threadIdx.x;
  if (i < n4) {
    f32x4 v = ((const f32x4*)src)[i];
    u16x4 o; o[0]=f2bfu(v[0]); o[1]=f2bfu(v[1]); o[2]=f2bfu(v[2]); o[3]=f2bfu(v[3]);
    ((u16x4*)dst)[i] = o;
  }
}

// ================= r2 precompute: r2[b,t,h] = 1/max(||k*k_k||^2, 1e-24) =================
__global__ __launch_bounds__(256) void rnorm_k(
    const u16* __restrict__ kb, const float* __restrict__ kkw, float* __restrict__ r2)
{
  const size_t bt = blockIdx.x;
  const int tid = threadIdx.x;
  const int c0 = tid << 3;                      // 8 channels per thread
  u16x8 kv8 = *(const u16x8*)(kb + bt*2048 + c0);
  f32x4 ka_ = *(const f32x4*)(kkw + c0);
  f32x4 kb_ = *(const f32x4*)(kkw + c0 + 4);
  float s = 0.f;
  #pragma unroll
  for (int e=0;e<4;e++){ float kk = bfu2f(kv8[e])*ka_[e];   s = fmaf(kk,kk,s); }
  #pragma unroll
  for (int e=0;e<4;e++){ float kk = bfu2f(kv8[4+e])*kb_[e]; s = fmaf(kk,kk,s); }
  s += __shfl_xor(s, 1, 64);
  s += __shfl_xor(s, 2, 64);
  s += __shfl_xor(s, 4, 64);
  if ((tid & 7) == 0) r2[bt*32 + (tid>>3)] = 1.f/fmaxf(s, 1e-24f);
}

// ================= WKV scan (fallback, unchanged) =================
__global__ __launch_bounds__(64) __attribute__((amdgpu_waves_per_eu(1, 4)))
void scan_k(
    const u16* __restrict__ rb, const float* __restrict__ wb, const u16* __restrict__ kb,
    const float* __restrict__ vb, const u16* __restrict__ ab,
    const float* __restrict__ kkw, const float* __restrict__ kaw,
    const float* __restrict__ S0, float* __restrict__ yb, float* __restrict__ Sout, int T_)
{
  const int Hh = 2048, NHl = 32;
  const int blk = blockIdx.x;
  const int b = blk >> 5, h = blk & 31;
  const int lane = threadIdx.x;
  float S[64];
  const size_t sbase = (((size_t)b*NHl + h)*64 + lane)*64;
  #pragma unroll
  for (int i=0;i<64;i++) S[i] = S0[sbase+i];
  const float kkc = kkw[h*64+lane], kac = kaw[h*64+lane];
  __shared__ alignas(16) float lw[64], lkk[64], lka[64], lke[64], lr[64];
  size_t idx = (size_t)b*T_*Hh + (size_t)h*64 + lane;
  float rv = bfu2f(rb[idx]), wv = wb[idx], kv = bfu2f(kb[idx]), vv = vb[idx], av = bfu2f(ab[idx]);
  for (int t=0; t<T_; ++t) {
    float kk = kv * kkc;
    float ssum = kk*kk;
    #pragma unroll
    for (int m=1;m<64;m<<=1) ssum += __shfl_xor(ssum, m, 64);
    float inv = 1.f / fmaxf(sqrtf(ssum), 1e-12f);
    float kkn = kk * inv;
    float ke  = kv * (1.f + (av - 1.f)*kac);
    lw[lane]=wv; lkk[lane]=kkn; lka[lane]=kkn*av; lke[lane]=ke; lr[lane]=rv;
    const float vt = vv;
    __syncthreads();
    float nrv=0.f,nwv=0.f,nkv=0.f,nvv=0.f,nav=0.f;
    if (t+1 < T_) {
      const size_t ni = idx + Hh;
      nrv = bfu2f(rb[ni]); nwv = wb[ni]; nkv = bfu2f(kb[ni]); nvv = vb[ni]; nav = bfu2f(ab[ni]);
    }
    const f32x4* KK4 = (const f32x4*)lkk;
    const f32x4* W4  = (const f32x4*)lw;
    const f32x4* KA4 = (const f32x4*)lka;
    const f32x4* KE4 = (const f32x4*)lke;
    const f32x4* R4  = (const f32x4*)lr;
    float sa0=0.f,sa1=0.f,sa2=0.f,sa3=0.f;
    #pragma unroll
    for (int qq=0;qq<16;qq++){
      f32x4 k4 = KK4[qq];
      sa0 = fmaf(S[4*qq+0], k4[0], sa0);
      sa1 = fmaf(S[4*qq+1], k4[1], sa1);
      sa2 = fmaf(S[4*qq+2], k4[2], sa2);
      sa3 = fmaf(S[4*qq+3], k4[3], sa3);
    }
    const float sa = -((sa0+sa1)+(sa2+sa3));
    float y0=0.f,y1=0.f,y2=0.f,y3=0.f;
    #pragma unroll
    for (int qq=0;qq<16;qq++){
      f32x4 w4=W4[qq], a4=KA4[qq], e4=KE4[qq], r4=R4[qq];
      float s_;
      s_ = fmaf(vt, e4[0], fmaf(sa, a4[0], S[4*qq+0]*w4[0])); S[4*qq+0]=s_; y0 = fmaf(s_, r4[0], y0);
      s_ = fmaf(vt, e4[1], fmaf(sa, a4[1], S[4*qq+1]*w4[1])); S[4*qq+1]=s_; y1 = fmaf(s_, r4[1], y1);
      s_ = fmaf(vt, e4[2], fmaf(sa, a4[2], S[4*qq+2]*w4[2])); S[4*qq+2]=s_; y2 = fmaf(s_, r4[2], y2);
      s_ = fmaf(vt, e4[3], fmaf(sa, a4[3], S[4*qq+3]*w4[3])); S[4*qq+3]=s_; y3 = fmaf(s_, r4[3], y3);
    }
    yb[idx] = (y0+y1)+(y2+y3);
    __syncthreads();
    rv=nrv; wv=nwv; kv=nkv; vv=nvv; av=nav;
    idx += Hh;
  }
  #pragma unroll
  for (int i=0;i<64;i++) Sout[sbase+i] = S[i];
}

// ================= Phase A: per-chunk M+D (role 0) and U+ylocal (role 1) =================
// [R4-proven, 500us] 4 independent single-role waves per 256-thread WG, wave-private
// LDS slices, zero barriers.  Triple-buffered broadcast arrays + register prefetch.
// Role 0 (M): S=I, no v term; emits d_t = P_t.r_t -> Dbuf, final P -> Mbuf.
// Role 1 (U): S=0, full update; emits ylocal_t = U_t.r_t -> yb, final U -> Ubuf.
__global__ __launch_bounds__(256) void chunk_mu_k(
    const u16* __restrict__ rb, const float* __restrict__ wb, const u16* __restrict__ kb,
    const float* __restrict__ vb, const u16* __restrict__ ab,
    const float* __restrict__ kkw, const float* __restrict__ kaw,
    const float* __restrict__ r2b,
    float* __restrict__ Mbuf, float* __restrict__ Ubuf, float* __restrict__ Dbuf,
    float* __restrict__ yb, int T_, int NC)
{
  const int wid  = threadIdx.x >> 6;
  const int lane = threadIdx.x & 63;
  const int g    = blockIdx.x * 4 + wid;     // global unit = ch*2 + role
  const int ch   = g >> 1;
  const bool mrole = ((g & 1) == 0);
  const int c  = ch % NC;
  const int bh = ch / NC;
  const int b = bh >> 5, h = bh & 31;

  float S[64];
  #pragma unroll
  for (int i=0;i<64;i++) S[i] = (mrole && lane == i) ? 1.f : 0.f;  // constant index (rule #20)

  const int hc = h*64 + lane;
  const float kkc = kkw[hc], kac = kaw[hc];

  __shared__ alignas(16) float LB[4][3][5][64];   // [wave][buf][w,kk,ka,ke,r][chan]
  float (*Lw)[5][64] = LB[wid];

  size_t idx = ((size_t)b*T_ + (size_t)c*64)*2048 + hc;
  size_t r2i = ((size_t)b*T_ + (size_t)c*64)*32 + h;
  float* dD = Dbuf + (size_t)ch*4096 + lane;

  // prologue: step 0 -> buf0; prefetch step 1 into registers
  {
    const float kv = bfu2f(kb[idx]);
    const float av = bfu2f(ab[idx]);
    const float kk = kv*kkc;
    Lw[0][0][lane] = wb[idx];
    Lw[0][1][lane] = kk;
    Lw[0][2][lane] = kk*av;
    Lw[0][3][lane] = kv*(1.f+(av-1.f)*kac);
    Lw[0][4][lane] = bfu2f(rb[idx]);
  }
  float c_vv = mrole ? 0.f : vb[idx];
  float c_r2 = r2b[r2i];
  float p_r, p_k, p_w, p_a, p_v = 0.f, p_r2;
  {
    const size_t ni = idx + 2048;
    p_r = bfu2f(rb[ni]); p_k = bfu2f(kb[ni]); p_w = wb[ni]; p_a = bfu2f(ab[ni]);
    if (!mrole) p_v = vb[ni];
    p_r2 = r2b[r2i + 32];
  }

  int cur = 0;
  for (int j=0; j<64; ++j) {
    int nxt = cur + 1; if (nxt == 3) nxt = 0;
    // 1. stage step j+1 into buf nxt (values prefetched during step j-1)
    if (j+1 < 64) {
      const float kk = p_k*kkc;
      Lw[nxt][0][lane] = p_w;
      Lw[nxt][1][lane] = kk;
      Lw[nxt][2][lane] = kk*p_a;
      Lw[nxt][3][lane] = p_k*(1.f+(p_a-1.f)*kac);
      Lw[nxt][4][lane] = p_r;
    }
    const float n_vv = p_v, n_r2 = p_r2;
    // 2. issue global loads for step j+2
    float q_r=0.f,q_k=0.f,q_w=0.f,q_a=0.f,q_v=0.f,q_r2=0.f;
    if (j+2 < 64) {
      const size_t ni = idx + 4096;
      q_r = bfu2f(rb[ni]); q_k = bfu2f(kb[ni]); q_w = wb[ni]; q_a = bfu2f(ab[ni]);
      if (!mrole) q_v = vb[ni];
      q_r2 = r2b[r2i + 64];
    }
    // 3. compute step j from buf cur (written at start of step j-1 -> long landed)
    const f32x4* W4  = (const f32x4*)Lw[cur][0];
    const f32x4* KK4 = (const f32x4*)Lw[cur][1];
    const f32x4* KA4 = (const f32x4*)Lw[cur][2];
    const f32x4* KE4 = (const f32x4*)Lw[cur][3];
    const f32x4* R4  = (const f32x4*)Lw[cur][4];
    float sA0=0.f,sA1=0.f,sA2=0.f,sA3=0.f,sB0=0.f,sB1=0.f,sB2=0.f,sB3=0.f;
    #pragma unroll
    for (int qq=0;qq<8;qq++){
      f32x4 kA = KK4[qq];
      sA0 = fmaf(S[4*qq+0], kA[0], sA0);
      sA1 = fmaf(S[4*qq+1], kA[1], sA1);
      sA2 = fmaf(S[4*qq+2], kA[2], sA2);
      sA3 = fmaf(S[4*qq+3], kA[3], sA3);
      f32x4 kB = KK4[8+qq];
      sB0 = fmaf(S[32+4*qq+0], kB[0], sB0);
      sB1 = fmaf(S[32+4*qq+1], kB[1], sB1);
      sB2 = fmaf(S[32+4*qq+2], kB[2], sB2);
      sB3 = fmaf(S[32+4*qq+3], kB[3], sB3);
    }
    const float sa = -(((sA0+sB0)+(sA1+sB1)) + ((sA2+sB2)+(sA3+sB3))) * c_r2;
    const float vt = c_vv;
    float y0=0.f,y1=0.f,y2=0.f,y3=0.f;
    if (mrole) {
      #pragma unroll
      for (int qq=0;qq<16;qq++){
        f32x4 w4=W4[qq], a4=KA4[qq], r4=R4[qq];
        float s_;
        s_ = fmaf(sa, a4[0], S[4*qq+0]*w4[0]); S[4*qq+0]=s_; y0 = fmaf(s_, r4[0], y0);
        s_ = fmaf(sa, a4[1], S[4*qq+1]*w4[1]); S[4*qq+1]=s_; y1 = fmaf(s_, r4[1], y1);
        s_ = fmaf(sa, a4[2], S[4*qq+2]*w4[2]); S[4*qq+2]=s_; y2 = fmaf(s_, r4[2], y2);
        s_ = fmaf(sa, a4[3], S[4*qq+3]*w4[3]); S[4*qq+3]=s_; y3 = fmaf(s_, r4[3], y3);
      }
      dD[(size_t)j*64] = (y0+y1)+(y2+y3);        // d_t[lane]
    } else {
      #pragma unroll
      for (int qq=0;qq<16;qq++){
        f32x4 w4=W4[qq], a4=KA4[qq], e4=KE4[qq], r4=R4[qq];
        float s_;
        s_ = fmaf(vt, e4[0], fmaf(sa, a4[0], S[4*qq+0]*w4[0])); S[4*qq+0]=s_; y0 = fmaf(s_, r4[0], y0);
        s_ = fmaf(vt, e4[1], fmaf(sa, a4[1], S[4*qq+1]*w4[1])); S[4*qq+1]=s_; y1 = fmaf(s_, r4[1], y1);
        s_ = fmaf(vt, e4[2], fmaf(sa, a4[2], S[4*qq+2]*w4[2])); S[4*qq+2]=s_; y2 = fmaf(s_, r4[2], y2);
        s_ = fmaf(vt, e4[3], fmaf(sa, a4[3], S[4*qq+3]*w4[3])); S[4*qq+3]=s_; y3 = fmaf(s_, r4[3], y3);
      }
      yb[idx] = (y0+y1)+(y2+y3);                 // ylocal_t[lane]
    }
    // rotate pipeline
    cur = nxt;
    c_vv = n_vv; c_r2 = n_r2;
    p_r=q_r; p_k=q_k; p_w=q_w; p_a=q_a; p_v=q_v; p_r2=q_r2;
    idx += 2048; r2i += 32;
  }
  float* fd = (mrole ? Mbuf : Ubuf) + (size_t)ch*4096 + (size_t)lane*64;
  #pragma unroll
  for (int qq=0;qq<16;qq++)
    *(f32x4*)(fd + 4*qq) = f32x4{S[4*qq+0],S[4*qq+1],S[4*qq+2],S[4*qq+3]};
}

// ================= Phase B: sequential inter-chunk state propagation =================
// NOTE: SSbuf aliases Ubuf (SS overlays U).  Each thread loads its U element
// BEFORE storing SS to the same address (same-thread same-address -> ordered),
// so no __restrict__ on these two params.
__global__ __launch_bounds__(256) void propagate_k(
    const float* __restrict__ Mbuf, const float* Ubuf,
    const float* __restrict__ S0, float* SSbuf, float* __restrict__ Sout, int NC)
{
  const int bh   = blockIdx.x >> 2;
  const int v0r  = (blockIdx.x & 3) * 16;
  const int tid  = threadIdx.x;
  const int lane = tid & 63;
  const int wvv  = tid >> 6;

  __shared__ float MT[64*65];
  __shared__ float Srow[16][64];

  #pragma unroll
  for (int i=0;i<4;i++) {
    const int v = v0r + wvv*4 + i;
    Srow[wvv*4+i][lane] = S0[((size_t)bh*64 + v)*64 + lane];
  }

  const size_t mbase = (size_t)bh * NC * 4096;
  f32x4 mreg[4];
  #pragma unroll
  for (int it=0; it<4; ++it)
    mreg[it] = *(const f32x4*)(Mbuf + mbase + it*1024 + tid*4);

  for (int c=0; c<NC; ++c) {
    const size_t chB = mbase + (size_t)c*4096;
    #pragma unroll
    for (int it=0; it<4; ++it) {
      const int base = it*1024 + tid*4;
      const int j = base >> 6;
      const int k = base & 63;
      #pragma unroll
      for (int e=0;e<4;e++) MT[(k+e)*65 + j] = mreg[it][e];
    }
    __syncthreads();
    if (c+1 < NC) {
      #pragma unroll
      for (int it=0; it<4; ++it)
        mreg[it] = *(const f32x4*)(Mbuf + chB + 4096 + it*1024 + tid*4);
    }
    float u[4];
    #pragma unroll
    for (int i=0;i<4;i++)
      u[i] = Ubuf[chB + (size_t)(v0r + wvv*4 + i)*64 + lane];
    #pragma unroll
    for (int i=0;i<4;i++)
      SSbuf[chB + (size_t)(v0r + wvv*4 + i)*64 + lane] = Srow[wvv*4+i][lane];
    float acc[4] = {0.f,0.f,0.f,0.f};
    #pragma unroll
    for (int j4=0; j4<16; ++j4) {
      float m0_ = MT[lane*65 + j4*4 + 0];
      float m1_ = MT[lane*65 + j4*4 + 1];
      float m2_ = MT[lane*65 + j4*4 + 2];
      float m3_ = MT[lane*65 + j4*4 + 3];
      #pragma unroll
      for (int i=0;i<4;i++) {
        f32x4 s4 = *(const f32x4*)&Srow[wvv*4+i][j4*4];
        acc[i] = fmaf(s4[0], m0_, acc[i]);
        acc[i] = fmaf(s4[1], m1_, acc[i]);
        acc[i] = fmaf(s4[2], m2_, acc[i]);
        acc[i] = fmaf(s4[3], m3_, acc[i]);
      }
    }
    #pragma unroll
    for (int i=0;i<4;i++) Srow[wvv*4+i][lane] = acc[i] + u[i];
    __syncthreads();
  }
  #pragma unroll
  for (int i=0;i<4;i++) {
    const int v = v0r + wvv*4 + i;
    Sout[((size_t)bh*64 + v)*64 + lane] = Srow[wvv*4+i][lane];
  }
}

// ================= Phase C: y correction  y[t][v] += sum_j SS[v][j] * D[t][j] ==========
// [R5-verified-correct] 4-wave WG per chunk-head: SS and D staged once
// cooperatively; each wave handles 16 t-rows (no 64-long serial loop, 4x the
// wave count of the 1-wave version).  D rows read wave-uniform -> conflict-free.
__global__ __launch_bounds__(256) void ycorr_k(
    const float* __restrict__ SSbuf, const float* __restrict__ Dbuf,
    float* __restrict__ yb, int T_, int NC)
{
  const int ch = blockIdx.x;
  const int c  = ch % NC;
  const int bh = ch / NC;
  const int b = bh >> 5, h = bh & 31;
  const int tid = threadIdx.x;
  const int wid = tid >> 6, lane = tid & 63;

  __shared__ alignas(16) float Sl[64*68];
  __shared__ alignas(16) float Dl[64*68];

  {
    const float* sg = SSbuf + (size_t)ch*4096;
    const float* dg = Dbuf  + (size_t)ch*4096;
    #pragma unroll
    for (int i=0;i<4;i++){
      const int o = i*1024 + tid*4;
      f32x4 vs = *(const f32x4*)(sg + o);
      f32x4 vd = *(const f32x4*)(dg + o);
      const int rr = o >> 6, cc = o & 63;
      *(f32x4*)&Sl[rr*68 + cc] = vs;
      *(f32x4*)&Dl[rr*68 + cc] = vd;
    }
  }
  __syncthreads();
  float ss[64];
  #pragma unroll
  for (int qq=0;qq<16;qq++){
    f32x4 v = *(const f32x4*)&Sl[lane*68 + 4*qq];
    ss[4*qq+0]=v[0]; ss[4*qq+1]=v[1]; ss[4*qq+2]=v[2]; ss[4*qq+3]=v[3];
  }
  size_t idx = ((size_t)b*T_ + (size_t)c*64 + (size_t)wid*16)*2048 + (size_t)h*64 + lane;
  for (int tt=0; tt<16; ++tt) {
    const f32x4* D4 = (const f32x4*)&Dl[(wid*16 + tt)*68];
    float a0=0.f,a1=0.f,a2=0.f,a3=0.f;
    #pragma unroll
    for (int qq=0;qq<16;qq++){
      f32x4 d4 = D4[qq];
      a0 = fmaf(ss[4*qq+0], d4[0], a0);
      a1 = fmaf(ss[4*qq+1], d4[1], a1);
      a2 = fmaf(ss[4*qq+2], d4[2], a2);
      a3 = fmaf(ss[4*qq+3], d4[3], a3);
    }
    yb[idx] = yb[idx] + ((a0+a1)+(a2+a3));
    idx += 2048;
  }
}

// ================= post: groupnorm + rk*v + gate -> bf16 z; + v_first passthrough =====
// vb aliases vout (vb = v buffer, vout = same buffer rewritten with vfirst).
// Same-thread read-before-write at the same idx -> ordered; no __restrict__ on the pair.
__global__ __launch_bounds__(256) void post_k(
    const float* __restrict__ yb, const u16* __restrict__ rb, const u16* __restrict__ kb,
    const u16* __restrict__ ab, const u16* __restrict__ gb, const float* vb,
    const float* __restrict__ kaw, const float* __restrict__ rkw,
    const float* __restrict__ lnw, const float* __restrict__ lnb, u16* __restrict__ zb,
    const float* __restrict__ vf, float* vout)
{
  const int wid = threadIdx.x >> 6, lane = threadIdx.x & 63;
  const size_t unit = (size_t)blockIdx.x*4 + wid;
  const size_t bt = unit >> 5; const int h = (int)(unit & 31);
  const size_t idx = bt*2048 + (size_t)h*64 + lane;
  const int hc = h*64 + lane;
  const float yv = yb[idx];
  const float rv = bfu2f(rb[idx]), kv = bfu2f(kb[idx]), av = bfu2f(ab[idx]);
  const float vbv = vb[idx];
  const float ke = kv*(1.f + (av-1.f)*kaw[hc]);
  float s1 = yv, s2 = yv*yv, rk = rv*ke*rkw[hc];
  #pragma unroll
  for (int m=1;m<64;m<<=1){
    s1 += __shfl_xor(s1,m,64);
    s2 += __shfl_xor(s2,m,64);
    rk += __shfl_xor(rk,m,64);
  }
  const float mean = s1 * (1.f/64.f);
  const float var  = s2 * (1.f/64.f) - mean*mean;
  const float rstd = rsqrtf(var + 6.4e-4f);
  const float zn = (yv-mean)*rstd*lnw[hc] + lnb[hc] + rk*vbv;
  zb[idx] = f2bfu(zn * bfu2f(gb[idx]));
  vout[idx] = vf[idx];                 // v_first passthrough (v value consumed above)
}

// ================= host =================
extern "C" void kernel_launch(void* const* d_in, const int* in_sizes, int n_in,
                              void* d_out, int out_size, void* d_ws, size_t ws_size,
                              hipStream_t stream)
{
  const float* x      = (const float*)d_in[0];
  const float* shift  = (const float*)d_in[1];
  const float* wkv0   = (const float*)d_in[2];
  const float* vfirst = (const float*)d_in[3];
  const float* xr = (const float*)d_in[4];
  const float* xw = (const float*)d_in[5];
  const float* xk = (const float*)d_in[6];
  const float* xv = (const float*)d_in[7];
  const float* xa = (const float*)d_in[8];
  const float* xg = (const float*)d_in[9];
  const float* w0 = (const float*)d_in[10];
  const float* w1 = (const float*)d_in[11];
  const float* w2 = (const float*)d_in[12];
  const float* a0 = (const float*)d_in[13];
  const float* a1 = (const float*)d_in[14];
  const float* a2 = (const float*)d_in[15];
  const float* v0 = (const float*)d_in[16];
  const float* v1 = (const float*)d_in[17];
  const float* v2 = (const float*)d_in[18];
  const float* g1 = (const float*)d_in[19];
  const float* g2 = (const float*)d_in[20];
  const float* k_k = (const float*)d_in[21];
  const float* k_a = (const float*)d_in[22];
  const float* r_k = (const float*)d_in[23];
  const float* W_r = (const float*)d_in[24];
  const float* W_k = (const float*)d_in[25];
  const float* W_v = (const float*)d_in[26];
  const float* W_o = (const float*)d_in[27];
  const float* ln_w = (const float*)d_in[28];
  const float* ln_b = (const float*)d_in[29];

  const int H = 2048, NH = 32;
  const int BH = in_sizes[1];
  const int B  = BH / H;
  const long BTH = (long)in_sizes[0];
  const int T  = (int)(BTH / BH);
  const int M  = (int)(BTH / H);

  float* out0 = (float*)d_out;
  float* out1 = out0 + BTH;
  float* out2 = out1 + BH;
  float* out3 = out2 + (size_t)B*NH*64*64;

  // ---- workspace layout (unchanged total) ----
  char* ws = (char*)d_ws;
  u16* mixb = (u16*)ws;  ws += (size_t)BTH*12;   // region A: 6 bf16 mixed bufs
  u16* xr_b = mixb + 0*BTH;
  u16* xw_b = mixb + 1*BTH;
  u16* xk_b = mixb + 2*BTH;
  u16* xv_b = mixb + 3*BTH;
  u16* xa_b = mixb + 4*BTH;
  u16* xg_b = mixb + 5*BTH;
  // region A reuse (mixed bufs dead after big GEMMs):
  //   phase A writes M, U, D;  propagate overlays SS onto U (U read-then-write,
  //   same thread+address);  phase C reads SS(=U region) + D;  post overlays zb16
  //   onto the M region (M dead after propagate).
  float* Mbuf  = (float*)mixb;           // BTH f32
  float* Ubuf  = Mbuf + BTH;
  float* Dbuf  = Ubuf + BTH;
  float* SSbuf = Ubuf;                   // alias: SS overlays U
  u16*   zb16  = (u16*)mixb;             // post phase
  u16* rb   = (u16*)ws;  ws += BTH*2;
  u16* kb   = (u16*)ws;  ws += BTH*2;
  u16* ab   = (u16*)ws;  ws += BTH*2;
  u16* gb   = (u16*)ws;  ws += BTH*2;
  u16* wr16 = (u16*)ws;  ws += (size_t)H*H*2;
  u16* wk16 = (u16*)ws;  ws += (size_t)H*H*2;
  u16* wv16 = (u16*)ws;  ws += (size_t)H*H*2;
  u16* wo16 = (u16*)ws;  ws += (size_t)H*H*2;
  u16* h1w  = (u16*)ws;  ws += (size_t)M*96*2;
  u16* h1a  = (u16*)ws;  ws += (size_t)M*96*2;
  u16* h1v  = (u16*)ws;  ws += (size_t)M*64*2;
  u16* h1g  = (u16*)ws;  ws += (size_t)M*256*2;
  float* dxz = (float*)ws; ws += BTH*4;          // w_raw -> w (f32)
  float* r2b = (float*)h1w;                      // M*NH*4 = 1 MB <= M*96*2; h1w dead after w2 gemm
  const size_t ws_need = (size_t)(ws - (char*)d_ws);
  const bool chunked = (ws_size >= ws_need) && (T % 64 == 0);
  const bool big_ok  = (M % 128 == 0);           // H==2048 always ok
  (void)n_in; (void)out_size;

  const dim3 blk(256);
  auto gg  = [&](int N){ return dim3(M/64, (N+63)/64); };
  auto gg128 = [&](int N){ return dim3(M/128, N/128); };

  // 1. fused token-shift + 6-way mix + bf16 cast; out1 = x[:,-1]
  mix_cast_k<<<dim3((unsigned)((BTH/4 + 255)/256)), blk, 0, stream>>>(
      x, shift, xr, xw, xk, xv, xa, xg, xr_b, xw_b, xk_b, xv_b, xa_b, xg_b, out1, T, B);

  // 2. weights -> bf16
  {
    const long n4 = (long)H*H/4;
    const dim3 gw((unsigned)((n4 + 255)/256));
    castw_k<<<gw, blk, 0, stream>>>(W_r, wr16, n4);
    castw_k<<<gw, blk, 0, stream>>>(W_k, wk16, n4);
    castw_k<<<gw, blk, 0, stream>>>(W_v, wv16, n4);
    castw_k<<<gw, blk, 0, stream>>>(W_o, wo16, n4);
  }

  // 3. stage-1 LoRA projections (bf16 A); tanh fused into w1, sigmoid into g1
  gemm_k<false,false,true,true,4><<<gg(96),  blk, 0, stream>>>(xw_b, nullptr, nullptr, w1, h1w, M, 96,  H);
  gemm_k<false,false,true,true  ><<<gg(96),  blk, 0, stream>>>(xa_b, nullptr, nullptr, a1, h1a, M, 96,  H);
  gemm_k<false,false,true,true  ><<<gg(64),  blk, 0, stream>>>(xv_b, nullptr, nullptr, v1, h1v, M, 64,  H);
  gemm_k<false,false,true,true,5><<<gg(256), blk, 0, stream>>>(xg_b, nullptr, nullptr, g1, h1g, M, 256, H);

  // 4. big projections (bf16 x bf16)
  if (big_ok) {
    gemm128_k<true ><<<gg128(H), blk, 0, stream>>>(xr_b, wr16, rb,   M, H, H);
    gemm128_k<true ><<<gg128(H), blk, 0, stream>>>(xk_b, wk16, kb,   M, H, H);
    gemm128_k<false><<<gg128(H), blk, 0, stream>>>(xv_b, wv16, out3, M, H, H);
  } else {
    gemm_k<false,true,true,true ><<<gg(H), blk, 0, stream>>>(xr_b, nullptr, nullptr, W_r, rb,   M, H, H);
    gemm_k<false,true,true,true ><<<gg(H), blk, 0, stream>>>(xk_b, nullptr, nullptr, W_k, kb,   M, H, H);
    gemm_k<false,true,true,false><<<gg(H), blk, 0, stream>>>(xv_b, nullptr, nullptr, W_v, out3, M, H, H);
  }

  // 5. stage-2 LoRA projections; w-transform fused into w2, a-sigmoid into a2,
  //    v-blend into v2 epilogue
  gemm_k<false,false,true,false,2><<<gg(H), blk, 0, stream>>>(h1w, nullptr, w0, w2, dxz, M, H, 96);
  // h1w dead from here -> r2b overlay becomes live; kb ready since step 4
  rnorm_k<<<dim3((unsigned)M), blk, 0, stream>>>(kb, k_k, r2b);
  gemm_k<false,false,true,true,3 ><<<gg(H), blk, 0, stream>>>(h1a, nullptr, a0, a2, ab,  M, H, 96);
  gemm_k<false,false,true,false,1><<<gg(H), blk, 0, stream>>>(h1v, vfirst,  v0, v2, out3, M, H, 64);
  gemm_k<false,false,true,true   ><<<gg(H), blk, 0, stream>>>(h1g, nullptr, nullptr, g2, gb,  M, H, 256);

  // 6. chunked WKV: phase A (M+D, U+ylocal) -> propagate (SS) -> ycorr (y += SS.d)
  if (chunked) {
    const int NC = T / 64;
    const int CH = B * NH * NC;                  // NH=32 -> 2*CH always %4==0
    chunk_mu_k <<<dim3((unsigned)(2*CH/4)), blk, 0, stream>>>(rb, dxz, kb, out3, ab, k_k, k_a, r2b,
                                                              Mbuf, Ubuf, Dbuf, out0, T, NC);
    propagate_k<<<dim3(B*NH*4), blk, 0, stream>>>(Mbuf, Ubuf, wkv0, SSbuf, out2, NC);
    ycorr_k    <<<dim3(CH),     blk, 0, stream>>>(SSbuf, Dbuf, out0, T, NC);
  } else {
    scan_k<<<dim3(B*NH), dim3(64), 0, stream>>>(rb, dxz, kb, out3, ab, k_k, k_a, wkv0, out0, out2, T);
  }

  // 7. groupnorm + rk*v + gate -> bf16 z; v_first passthrough fused (out3 <- vfirst)
  post_k<<<dim3((unsigned)((size_t)M*NH/4)), blk, 0, stream>>>(out0, rb, kb, ab, gb, out3,
                                                               k_a, r_k, ln_w, ln_b, zb16,
                                                               vfirst, out3);

  // 8. out = z @ W_o.T
  if (big_ok) {
    gemm128_k<false><<<gg128(H), blk, 0, stream>>>(zb16, wo16, out0, M, H, H);
  } else {
    gemm_k<false,true,true,false><<<gg(H), blk, 0, stream>>>(zb16, nullptr, nullptr, W_o, out0, M, H, H);
  }
}